// Round 5
// baseline (15.401 us; speedup 1.0000x reference)
//
#include <hip/hip_runtime.h>

// out[b,o] = min_i max(x[b,i], w[i,o])   (forward of STE expr == hard min)
// B=512, I=512, O=1024, fp32, values uniform in [0,1).
//
// One 512-thread block per row b:
//  Phase A: counting-sort x[b,:] into 256 value buckets in LDS (once per row).
//  Phase B: 8 independent waves scan entries in bucket-ascending order with a
//           running min; exit when no lane's min exceeds the next entry's
//           bucket lower bound (exact to ~6e-8). Scan is software-pipelined:
//           chunk k+1's LDS entries + w loads are issued before chunk k's
//           min-updates + exit check, hiding LDS and L2 latency.

#define B_DIM 512
#define I_DIM 512
#define O_DIM 1024
#define NBUCK 256
#define U 8

typedef float float2v __attribute__((ext_vector_type(2)));

#define LOADC(K, XS, W)                                                          \
  _Pragma("unroll") for (int u = 0; u < U; ++u) {                                \
    const unsigned long long kk = s[(K) + u];                                    \
    const int row = __builtin_amdgcn_readfirstlane((int)(unsigned)kk);           \
    const unsigned xb = (unsigned)__builtin_amdgcn_readfirstlane((int)(kk >> 32)); \
    XS[u] = __uint_as_float(xb);                                                 \
    const float* p = w + (size_t)row * O_DIM; /* scalar base + vector offset */  \
    W[u] = *reinterpret_cast<const float2v*>(p + oa);                            \
  }

__global__ __launch_bounds__(512, 4) void SmoothSTEMinMax_fused(
    const float* __restrict__ x,     // [B, I]
    const float* __restrict__ w,     // [I, O]
    float* __restrict__ out) {       // [B, O]
  __shared__ unsigned int hist[NBUCK];
  __shared__ unsigned int wssum[4];
  __shared__ unsigned long long s[I_DIM];   // (x bits << 32) | idx, bucket-ordered

  const int t = threadIdx.x;
  const int b = blockIdx.x;
  const int lane = t & 63;

  // ---- Phase A: counting sort by value bucket (one value per thread) ----
  const float xval = x[b * I_DIM + t];
  int bb = (int)(xval * 256.0f);
  bb = bb > 255 ? 255 : (bb < 0 ? 0 : bb);
  if (t < NBUCK) hist[t] = 0;
  __syncthreads();
  atomicAdd(&hist[bb], 1u);
  __syncthreads();

  // exclusive prefix sum over 256 counters (first 4 waves)
  unsigned v = 0, cnt = 0;
  if (t < NBUCK) {
    cnt = hist[t];
    v = cnt;
#pragma unroll
    for (int d = 1; d < 64; d <<= 1) {
      const unsigned n = __shfl_up(v, d, 64);
      if (lane >= d) v += n;
    }
    if (lane == 63) wssum[t >> 6] = v;
  }
  __syncthreads();
  if (t < NBUCK) {
    unsigned add = 0;
#pragma unroll
    for (int ww = 0; ww < 4; ++ww)
      if (ww < (t >> 6)) add += wssum[ww];
    hist[t] = v + add - cnt;   // bucket cursor
  }
  __syncthreads();
  {
    const unsigned pos = atomicAdd(&hist[bb], 1u);
    s[pos] = ((unsigned long long)__float_as_uint(xval) << 32) | (unsigned)t;
  }
  __syncthreads();

  // ---- Phase B: pipelined early-exit scan (waves independent) ----
  const int wv_ = t >> 6;
  const int oa = wv_ * 128 + lane * 2;    // two contiguous outputs per lane
  float A0 = 3.402823466e+38f, A1 = A0;

  float xsA[U], xsB[U];
  float2v wA[U], wB[U];

  LOADC(0, xsA, wA);
  int k = 0;
  while (true) {
    // -- half 1: compute A-chunk, prefetch into B --
    {
      const bool last = (k + U >= I_DIM);
      if (!last) LOADC(k + U, xsB, wB);
#pragma unroll
      for (int u = 0; u < U; ++u) {
        A0 = fminf(A0, fmaxf(xsA[u], wA[u].x));
        A1 = fminf(A1, fmaxf(xsA[u], wA[u].y));
      }
      k += U;
      if (last) break;
      const int bn = (int)(xsB[0] * 256.0f);         // next entry's bucket
      const float thresh = (float)bn * 0.00390625f;  // bucket lower bound
      if (!__any(A0 > thresh || A1 > thresh)) break; // exact early exit
    }
    // -- half 2: compute B-chunk, prefetch into A --
    {
      const bool last = (k + U >= I_DIM);
      if (!last) LOADC(k + U, xsA, wA);
#pragma unroll
      for (int u = 0; u < U; ++u) {
        A0 = fminf(A0, fmaxf(xsB[u], wB[u].x));
        A1 = fminf(A1, fmaxf(xsB[u], wB[u].y));
      }
      k += U;
      if (last) break;
      const int bn = (int)(xsA[0] * 256.0f);
      const float thresh = (float)bn * 0.00390625f;
      if (!__any(A0 > thresh || A1 > thresh)) break;
    }
  }

  float2v r;
  r.x = A0;
  r.y = A1;
  *reinterpret_cast<float2v*>(&out[b * O_DIM + oa]) = r;
}

extern "C" void kernel_launch(void* const* d_in, const int* in_sizes, int n_in,
                              void* d_out, int out_size, void* d_ws, size_t ws_size,
                              hipStream_t stream) {
  const float* x = (const float*)d_in[0];   // [512, 512]
  const float* w = (const float*)d_in[1];   // [512, 1024]
  float* out = (float*)d_out;               // [512, 1024]

  SmoothSTEMinMax_fused<<<B_DIM, 512, 0, stream>>>(x, w, out);
}

// Round 6
// 14.206 us; speedup vs baseline: 1.0841x; 1.0841x over previous
//
#include <hip/hip_runtime.h>

// out[b,o] = min_i max(x[b,i], w[i,o])   (forward of STE expr == hard min)
// B=512, I=512, O=1024, fp32, values uniform in [0,1).
//
// One 1024-thread block per row b (2 blocks/CU -> 32 waves/CU = 8/SIMD):
//  Phase A: counting-sort x[b,:] into 256 value buckets in LDS (once per row).
//  Phase B: 16 waves, one output per lane (o = threadIdx.x). Scan entries in
//           bucket-ascending order with running min A; wave exits when no lane
//           has A > bucket_lo(next entry) — exact to ~6e-8. Depth-1 pipelined:
//           chunk k+1's LDS entries + w loads issue before chunk k's compute.

#define B_DIM 512
#define I_DIM 512
#define O_DIM 1024
#define NBUCK 256
#define U 8

// loads U sorted entries starting at K: x value -> SGPR (via readfirstlane),
// w row -> scalar base, per-lane w element via loop-invariant offset o.
#define LOADC(K, XS, W)                                                            \
  _Pragma("unroll") for (int u = 0; u < U; ++u) {                                  \
    const unsigned long long kk = s[(K) + u]; /* uniform-address LDS broadcast */  \
    const int row = __builtin_amdgcn_readfirstlane((int)(unsigned)kk);             \
    const unsigned xb = (unsigned)__builtin_amdgcn_readfirstlane((int)(kk >> 32)); \
    XS[u] = __uint_as_float(xb);                                                   \
    W[u] = w[(size_t)row * O_DIM + o]; /* SGPR base + invariant voffset */         \
  }

__global__ __launch_bounds__(1024, 8) void SmoothSTEMinMax_fused(
    const float* __restrict__ x,     // [B, I]
    const float* __restrict__ w,     // [I, O]
    float* __restrict__ out) {       // [B, O]
  __shared__ unsigned int hist[NBUCK];
  __shared__ unsigned int wssum[4];
  __shared__ unsigned long long s[I_DIM];   // (x bits << 32) | idx, bucket-ordered

  const int t = threadIdx.x;
  const int b = blockIdx.x;
  const int lane = t & 63;

  // ---- Phase A: counting sort by value bucket (threads 0..511 active) ----
  float xval = 0.0f;
  int bb = 0;
  if (t < I_DIM) {
    xval = x[b * I_DIM + t];
    bb = (int)(xval * 256.0f);
    bb = bb > 255 ? 255 : (bb < 0 ? 0 : bb);
  }
  if (t < NBUCK) hist[t] = 0;
  __syncthreads();
  if (t < I_DIM) atomicAdd(&hist[bb], 1u);
  __syncthreads();

  // exclusive prefix sum over 256 counters (first 4 waves)
  unsigned v = 0, cnt = 0;
  if (t < NBUCK) {
    cnt = hist[t];
    v = cnt;
#pragma unroll
    for (int d = 1; d < 64; d <<= 1) {
      const unsigned n = __shfl_up(v, d, 64);
      if (lane >= d) v += n;
    }
    if (lane == 63) wssum[t >> 6] = v;
  }
  __syncthreads();
  if (t < NBUCK) {
    unsigned add = 0;
#pragma unroll
    for (int ww = 0; ww < 4; ++ww)
      if (ww < (t >> 6)) add += wssum[ww];
    hist[t] = v + add - cnt;   // bucket cursor
  }
  __syncthreads();
  if (t < I_DIM) {
    const unsigned pos = atomicAdd(&hist[bb], 1u);
    s[pos] = ((unsigned long long)__float_as_uint(xval) << 32) | (unsigned)t;
  }
  __syncthreads();

  // ---- Phase B: pipelined early-exit scan; one output per lane ----
  const int o = t;                 // wave wv covers o in [wv*64, wv*64+64)
  float A = 3.402823466e+38f;

  float xsA[U], xsB[U];
  float wA[U], wB[U];

  LOADC(0, xsA, wA);
  int k = 0;
  while (true) {
    // -- half 1: prefetch into B, compute A-chunk --
    {
      const bool last = (k + U >= I_DIM);
      if (!last) LOADC(k + U, xsB, wB);
#pragma unroll
      for (int u = 0; u < U; ++u) A = fminf(A, fmaxf(xsA[u], wA[u]));
      k += U;
      if (last) break;
      const int bn = (int)(xsB[0] * 256.0f);         // next entry's bucket
      const float thresh = (float)bn * 0.00390625f;  // bucket lower bound
      if (!__any(A > thresh)) break;                 // exact early exit
    }
    // -- half 2: prefetch into A, compute B-chunk --
    {
      const bool last = (k + U >= I_DIM);
      if (!last) LOADC(k + U, xsA, wA);
#pragma unroll
      for (int u = 0; u < U; ++u) A = fminf(A, fmaxf(xsB[u], wB[u]));
      k += U;
      if (last) break;
      const int bn = (int)(xsA[0] * 256.0f);
      const float thresh = (float)bn * 0.00390625f;
      if (!__any(A > thresh)) break;
    }
  }

  out[b * O_DIM + o] = A;
}

extern "C" void kernel_launch(void* const* d_in, const int* in_sizes, int n_in,
                              void* d_out, int out_size, void* d_ws, size_t ws_size,
                              hipStream_t stream) {
  const float* x = (const float*)d_in[0];   // [512, 512]
  const float* w = (const float*)d_in[1];   // [512, 1024]
  float* out = (float*)d_out;               // [512, 1024]

  SmoothSTEMinMax_fused<<<B_DIM, 1024, 0, stream>>>(x, w, out);
}

// Round 7
// 13.624 us; speedup vs baseline: 1.1304x; 1.0427x over previous
//
#include <hip/hip_runtime.h>

// out[b,o] = min_i max(x[b,i], w[i,o])   (forward of STE expr == hard min)
// B=512, I=512, O=1024, fp32, values uniform in [0,1).
//
// One 1024-thread block per row b (32 waves/CU):
//  Phase A: counting-sort x[b,:] into 256 value buckets in LDS (packed
//           entries: byteoff = i*4096, valbits).
//  Phase B: each wave pulls entries 0..127 into 4 VGPRs with ONE
//           ds_read_b128 (lane l holds entries 2l,2l+1), then broadcasts
//           each entry via v_readlane (compile-time lane index — VALU pipe,
//           zero LDS traffic). First 64 entries straight-line (no checks,
//           full load ILP); adaptive unrolled tail 64..127 with per-8
//           bucket-lower-bound exit; ~never-taken LDS fallback for 128+.
//           Exit bound is exact: entries after position k have bucket >=
//           bucket(entry k), so value >= floor(val_k*256)/256.

#define B_DIM 512
#define I_DIM 512
#define O_DIM 1024
#define NBUCK 256

#define RL(v_, l_) ((unsigned)__builtin_amdgcn_readlane((int)(v_), (l_)))

__global__ __launch_bounds__(1024, 8) void SmoothSTEMinMax_fused(
    const float* __restrict__ x,     // [B, I]
    const float* __restrict__ w,     // [I, O]
    float* __restrict__ out) {       // [B, O]
  __shared__ unsigned int hist[NBUCK];
  __shared__ unsigned int wssum[4];
  __shared__ unsigned int sdat[2 * I_DIM];   // [2e]=byteoff(i*4096), [2e+1]=valbits

  const int t = threadIdx.x;
  const int b = blockIdx.x;
  const int lane = t & 63;

  // ---- Phase A: counting sort by value bucket (threads 0..511 active) ----
  float xval = 0.0f;
  int bb = 0;
  if (t < I_DIM) {
    xval = x[b * I_DIM + t];
    bb = (int)(xval * 256.0f);
    bb = bb > 255 ? 255 : (bb < 0 ? 0 : bb);
  }
  if (t < NBUCK) hist[t] = 0;
  __syncthreads();
  if (t < I_DIM) atomicAdd(&hist[bb], 1u);
  __syncthreads();

  unsigned v = 0, cnt = 0;
  if (t < NBUCK) {
    cnt = hist[t];
    v = cnt;
#pragma unroll
    for (int d = 1; d < 64; d <<= 1) {
      const unsigned n = __shfl_up(v, d, 64);
      if (lane >= d) v += n;
    }
    if (lane == 63) wssum[t >> 6] = v;
  }
  __syncthreads();
  if (t < NBUCK) {
    unsigned add = 0;
#pragma unroll
    for (int ww = 0; ww < 4; ++ww)
      if (ww < (t >> 6)) add += wssum[ww];
    hist[t] = v + add - cnt;   // bucket cursor
  }
  __syncthreads();
  if (t < I_DIM) {
    const unsigned pos = atomicAdd(&hist[bb], 1u);
    sdat[2 * pos] = (unsigned)t * (unsigned)(O_DIM * 4);  // byte offset of w row
    sdat[2 * pos + 1] = __float_as_uint(xval);
  }
  __syncthreads();

  // ---- Phase B: register-broadcast scan, one output per lane ----
  const unsigned o4 = (unsigned)t * 4u;
  const char* wb = reinterpret_cast<const char*>(w);
  float A = 3.402823466e+38f;

  // entries 0..127 -> 4 VGPRs/lane (lane l: entries 2l, 2l+1)
  const uint4 q = *reinterpret_cast<const uint4*>(&sdat[4 * lane]);

  // straight-line first 64 entries: zero checks, full global-load ILP
#pragma unroll
  for (int c = 0; c < 8; ++c) {
    float wv[8], xv[8];
#pragma unroll
    for (int e = 0; e < 8; ++e) {
      const int g = c * 8 + e;
      const unsigned off = RL((g & 1) ? q.z : q.x, g >> 1);
      const unsigned xb  = RL((g & 1) ? q.w : q.y, g >> 1);
      xv[e] = __uint_as_float(xb);
      wv[e] = *reinterpret_cast<const float*>(wb + (off + o4));
    }
#pragma unroll
    for (int e = 0; e < 8; ++e) A = fminf(A, fmaxf(xv[e], wv[e]));
  }

  int k = 64;
  // register-resident adaptive tail: entries 64..127, exit check per 8
#pragma unroll
  for (int c = 8; c < 16; ++c) {
    const float nx = __uint_as_float(RL(q.y, 4 * c));       // value of entry 8c
    const float th = (float)(int)(nx * 256.0f) * 0.00390625f;  // bucket lower bound
    if (!__any(A > th)) break;                               // exact early exit
#pragma unroll
    for (int e = 0; e < 8; ++e) {
      const int g = c * 8 + e;
      const unsigned off = RL((g & 1) ? q.z : q.x, g >> 1);
      const unsigned xb  = RL((g & 1) ? q.w : q.y, g >> 1);
      const float wvv = *reinterpret_cast<const float*>(wb + (off + o4));
      A = fminf(A, fmaxf(__uint_as_float(xb), wvv));
    }
    k += 8;
  }

  // LDS fallback: entries 128..511 (P ~ 1e-12 per wave; correctness only)
  if (k >= 128) {
    while (k < I_DIM) {
      const float nx = __uint_as_float(
          (unsigned)__builtin_amdgcn_readfirstlane((int)sdat[2 * k + 1]));
      const float th = (float)(int)(nx * 256.0f) * 0.00390625f;
      if (!__any(A > th)) break;
#pragma unroll
      for (int u = 0; u < 8; ++u) {
        const unsigned off =
            (unsigned)__builtin_amdgcn_readfirstlane((int)sdat[2 * (k + u)]);
        const unsigned xb =
            (unsigned)__builtin_amdgcn_readfirstlane((int)sdat[2 * (k + u) + 1]);
        const float wvv = *reinterpret_cast<const float*>(wb + (off + o4));
        A = fminf(A, fmaxf(__uint_as_float(xb), wvv));
      }
      k += 8;
    }
  }

  out[b * O_DIM + t] = A;
}

extern "C" void kernel_launch(void* const* d_in, const int* in_sizes, int n_in,
                              void* d_out, int out_size, void* d_ws, size_t ws_size,
                              hipStream_t stream) {
  const float* x = (const float*)d_in[0];   // [512, 512]
  const float* w = (const float*)d_in[1];   // [512, 1024]
  float* out = (float*)d_out;               // [512, 1024]

  SmoothSTEMinMax_fused<<<B_DIM, 1024, 0, stream>>>(x, w, out);
}